// Round 6
// baseline (294.961 us; speedup 1.0000x reference)
//
#include <hip/hip_runtime.h>
#include <hip/hip_bf16.h>

#define NHEADS 16
#define HDIM 64
#define SEQ 2048
#define BATCH 4
#define DMODEL 1024
#define MTOT (BATCH * SEQ)

typedef short v8s __attribute__((ext_vector_type(8)));
typedef short v4s __attribute__((ext_vector_type(4)));
typedef float v4f __attribute__((ext_vector_type(4)));
typedef float v16f __attribute__((ext_vector_type(16)));
typedef unsigned int v4u __attribute__((ext_vector_type(4)));
typedef unsigned short u16;
typedef unsigned int u32;

__device__ __forceinline__ u16 f2bf(float f) {
    union { float f; unsigned u; } v; v.f = f;
    unsigned r = v.u + 0x7FFFu + ((v.u >> 16) & 1u);
    return (u16)(r >> 16);
}

// async global->LDS, 16B/lane; LDS dest = wave-uniform base + lane*16.
__device__ __forceinline__ void g2l16(const u16* g, short* l) {
    __builtin_amdgcn_global_load_lds(
        (const __attribute__((address_space(1))) u32*)g,
        (__attribute__((address_space(3))) u32*)l, 16, 0, 0);
}

// v_cvt_pk_bf16_f32: pack two f32 -> one u32 of 2 bf16 (lo=a, hi=b)
__device__ __forceinline__ unsigned pk_bf16(float a, float b) {
    unsigned r;
    asm("v_cvt_pk_bf16_f32 %0, %1, %2" : "=v"(r) : "v"(a), "v"(b));
    return r;
}
// v_permlane32_swap_b32: x[32..63] <-> y[0..31]
__device__ __forceinline__ void pl32swap(unsigned& x, unsigned& y) {
    asm("v_permlane32_swap_b32 %0, %1" : "+v"(x), "+v"(y));
}
// Build one PV A-fragment (16 keys) from 8 lane-local P values.
__device__ __forceinline__ v8s build_pa(float a0, float a1, float a2, float a3,
                                        float b0, float b1, float b2, float b3) {
    unsigned X  = pk_bf16(a0, a1);
    unsigned X2 = pk_bf16(a2, a3);
    unsigned Y  = pk_bf16(b0, b1);
    unsigned Y2 = pk_bf16(b2, b3);
    pl32swap(X, Y);
    pl32swap(X2, Y2);
    v4u w; w[0] = X; w[1] = X2; w[2] = Y; w[3] = Y2;
    return __builtin_bit_cast(v8s, w);
}

// ---------------------------------------------------------------------------
// Weight transpose body: src fp32 [k][n] -> dst bf16 [n][k].
// ---------------------------------------------------------------------------
__device__ __forceinline__ void transpose_body(
    const float* __restrict__ src, u16* __restrict__ dst, int k0, int n0)
{
    __shared__ __align__(8) short Ts[64 * 68];
    const int t = threadIdx.x;
    const int n4 = (t & 15) * 4, kl = t >> 4;
#pragma unroll
    for (int it = 0; it < 4; ++it) {
        int k = kl + 16 * it;
        v4f v = *(const v4f*)&src[(size_t)(k0 + k) * DMODEL + n0 + n4];
        v4s p;
#pragma unroll
        for (int e = 0; e < 4; ++e) p[e] = (short)f2bf(v[e]);
        *(v4s*)&Ts[k * 68 + n4] = p;
    }
    __syncthreads();
    const int nl = t >> 4, k4 = (t & 15) * 4;
#pragma unroll
    for (int it = 0; it < 4; ++it) {
        int n = nl + 16 * it;
        v4s o;
#pragma unroll
        for (int e = 0; e < 4; ++e) o[e] = Ts[(k4 + e) * 68 + n];
        *(v4s*)&dst[(size_t)(n0 + n) * DMODEL + k0 + k4] = o;
    }
}

__global__ __launch_bounds__(256)
void transpose_w(const float* __restrict__ src, u16* __restrict__ dst)
{
    transpose_body(src, dst, blockIdx.x * 64, blockIdx.y * 64);
}

// ---------------------------------------------------------------------------
// prep: fused {4x weight transpose} + {x fp32->bf16}. One dispatch (saved
// ~4us vs two in r4/r5 A/B).
// ---------------------------------------------------------------------------
__global__ __launch_bounds__(256)
void prep(const float* __restrict__ x, u16* __restrict__ xb,
          const float* __restrict__ s0, const float* __restrict__ s1,
          const float* __restrict__ s2, const float* __restrict__ s3,
          u16* __restrict__ wdst)
{
    const int blk = blockIdx.x;
    if (blk < 1024) {
        const int z = blk >> 8;
        const int rem = blk & 255;
        const float* src = (z == 0) ? s0 : (z == 1) ? s1 : (z == 2) ? s2 : s3;
        transpose_body(src, wdst + (size_t)z * DMODEL * DMODEL,
                       (rem & 15) * 64, (rem >> 4) * 64);
    } else {
        size_t i = ((size_t)(blk - 1024) * 256 + threadIdx.x) * 8;
        v4f a = *(const v4f*)&x[i];
        v4f b = *(const v4f*)&x[i + 4];
        v8s p;
#pragma unroll
        for (int e = 0; e < 4; ++e) p[e] = (short)f2bf(a[e]);
#pragma unroll
        for (int e = 0; e < 4; ++e) p[4 + e] = (short)f2bf(b[e]);
        *(v8s*)&xb[i] = p;
    }
}

// ---------------------------------------------------------------------------
// QKV epilogue. Q scale folds softmax 1/8 AND log2(e) (exp2 in attn).
// (r5 lesson: the d-contiguous-across-lanes scalar store pattern beats the
//  swapped-MFMA v4s-along-d variant — lanes stay coalesced in d.)
// ---------------------------------------------------------------------------
#define QSCALE (0.125f * 1.44269504088896f)

__device__ __forceinline__ void qkv_epilogue(
    v4f (&acc)[4][4], int which, int n0, int m0, int wn, int wm,
    int l15, int quad, u16* Qb, u16* Kb, u16* Vt)
{
    if (which == 2) {
#pragma unroll
        for (int i = 0; i < 4; ++i)
#pragma unroll
            for (int j = 0; j < 4; ++j) {
                int col = n0 + wn + j * 16 + l15;
                int h = col >> 6, d = col & 63;
                int m = m0 + wm + i * 16 + quad * 4;
                int b = m >> 11, n = m & (SEQ - 1);
                v4s pv;
#pragma unroll
                for (int r = 0; r < 4; ++r) pv[r] = (short)f2bf(acc[i][j][r]);
                *(v4s*)&Vt[((size_t)(b * NHEADS + h) * HDIM + d) * SEQ + n] = pv;
            }
    } else {
        u16* Ob = (which == 0) ? Qb : Kb;
        const float scale = (which == 0) ? QSCALE : 1.0f;
#pragma unroll
        for (int i = 0; i < 4; ++i)
#pragma unroll
            for (int j = 0; j < 4; ++j) {
                int col = n0 + wn + j * 16 + l15;
                int h = col >> 6, d = col & 63;
#pragma unroll
                for (int r = 0; r < 4; ++r) {
                    int m = m0 + wm + i * 16 + quad * 4 + r;
                    int b = m >> 11, n = m & (SEQ - 1);
                    Ob[((size_t)(b * NHEADS + h) * SEQ + n) * HDIM + d] =
                        f2bf(acc[i][j][r] * scale);
                }
            }
    }
}

// ---------------------------------------------------------------------------
// qkv fast: both operands bf16 via global_load_lds. BK=128 this round:
// halves the barrier-drain count (8 vs 16 k-iters; the 2-phase structure's
// dominant cost per m233). Occupancy held at 2 blocks/CU (LDS 2x64KB=128KB
// <= 160KB) so m132's occupancy confound doesn't apply. 64 MFMA per
// barrier-pair per wave.
// ---------------------------------------------------------------------------
__global__ __launch_bounds__(256, 2)
void qkv_fast(const u16* __restrict__ xb, const u16* __restrict__ Wt,
              u16* __restrict__ Qb, u16* __restrict__ Kb, u16* __restrict__ Vt)
{
    __shared__ __align__(16) short As[128 * 128];
    __shared__ __align__(16) short Bs[128 * 128];

    const int which = blockIdx.z;
    const u16* W = Wt + (size_t)which * DMODEL * DMODEL;

    const int n0 = blockIdx.x * 128;
    const int m0 = blockIdx.y * 128;
    const int t = threadIdx.x;
    const int lane = t & 63;
    const int l15 = lane & 15;
    const int quad = lane >> 4;
    const int wave = t >> 6;
    const int wm = (wave >> 1) * 64;
    const int wn = (wave & 1) * 64;
    const int srow = t >> 4;          // 0..15
    const int sc8 = (t & 15) * 8;     // 0..120

    v4f acc[4][4];
#pragma unroll
    for (int i = 0; i < 4; ++i)
#pragma unroll
        for (int j = 0; j < 4; ++j) acc[i][j] = {0.f, 0.f, 0.f, 0.f};

    for (int k0 = 0; k0 < DMODEL; k0 += 128) {
        __syncthreads();
#pragma unroll
        for (int c = 0; c < 8; ++c) {
            g2l16(&xb[(size_t)(m0 + c * 16 + srow) * DMODEL + k0 + sc8],
                  &As[(c * 16 + srow) * 128 + sc8]);
            g2l16(&W[(size_t)(n0 + c * 16 + srow) * DMODEL + k0 + sc8],
                  &Bs[(c * 16 + srow) * 128 + sc8]);
        }
        __syncthreads();

#pragma unroll
        for (int kh = 0; kh < 4; ++kh) {
            v8s af[4], bf[4];
#pragma unroll
            for (int i = 0; i < 4; ++i)
                af[i] = *(const v8s*)
                    &As[(wm + i * 16 + l15) * 128 + kh * 32 + quad * 8];
#pragma unroll
            for (int j = 0; j < 4; ++j)
                bf[j] = *(const v8s*)
                    &Bs[(wn + j * 16 + l15) * 128 + kh * 32 + quad * 8];
#pragma unroll
            for (int i = 0; i < 4; ++i)
#pragma unroll
                for (int j = 0; j < 4; ++j)
                    acc[i][j] = __builtin_amdgcn_mfma_f32_16x16x32_bf16(
                        af[i], bf[j], acc[i][j], 0, 0, 0);
        }
    }
    qkv_epilogue(acc, which, n0, m0, wn, wm, l15, quad, Qb, Kb, Vt);
}

// ---------------------------------------------------------------------------
// qkv fallback: A = x fp32 converted at staging. BK=32. (small-ws path)
// ---------------------------------------------------------------------------
__global__ __launch_bounds__(256, 2)
void qkv_slow(const float* __restrict__ x, const u16* __restrict__ Wt,
              u16* __restrict__ Qb, u16* __restrict__ Kb, u16* __restrict__ Vt)
{
    __shared__ __align__(16) short As[128 * 32];
    __shared__ __align__(16) short Bs[128 * 32];

    const int which = blockIdx.z;
    const u16* W = Wt + (size_t)which * DMODEL * DMODEL;

    const int n0 = blockIdx.x * 128;
    const int m0 = blockIdx.y * 128;
    const int t = threadIdx.x;
    const int lane = t & 63;
    const int l15 = lane & 15;
    const int quad = lane >> 4;
    const int wave = t >> 6;
    const int wm = (wave >> 1) * 64;
    const int wn = (wave & 1) * 64;
    const int srow = t >> 2;
    const int sc8 = (t & 3) * 8;

    v4f acc[4][4];
#pragma unroll
    for (int i = 0; i < 4; ++i)
#pragma unroll
        for (int j = 0; j < 4; ++j) acc[i][j] = {0.f, 0.f, 0.f, 0.f};

    for (int k0 = 0; k0 < DMODEL; k0 += 32) {
        __syncthreads();
        g2l16(&W[(size_t)(n0 + srow) * DMODEL + k0 + sc8], &Bs[srow * 32 + sc8]);
        g2l16(&W[(size_t)(n0 + 64 + srow) * DMODEL + k0 + sc8],
              &Bs[(64 + srow) * 32 + sc8]);
#pragma unroll
        for (int it = 0; it < 2; ++it) {
            int row = srow + 64 * it;
            const float* xp = &x[(size_t)(m0 + row) * DMODEL + k0 + sc8];
            v4f x0 = *(const v4f*)xp;
            v4f x1 = *(const v4f*)(xp + 4);
            v8s av;
#pragma unroll
            for (int e = 0; e < 4; ++e) av[e] = (short)f2bf(x0[e]);
#pragma unroll
            for (int e = 0; e < 4; ++e) av[4 + e] = (short)f2bf(x1[e]);
            *(v8s*)&As[row * 32 + sc8] = av;
        }
        __syncthreads();

        v8s af[4], bf[4];
#pragma unroll
        for (int i = 0; i < 4; ++i)
            af[i] = *(const v8s*)&As[(wm + i * 16 + l15) * 32 + quad * 8];
#pragma unroll
        for (int j = 0; j < 4; ++j)
            bf[j] = *(const v8s*)&Bs[(wn + j * 16 + l15) * 32 + quad * 8];
#pragma unroll
        for (int i = 0; i < 4; ++i)
#pragma unroll
            for (int j = 0; j < 4; ++j)
                acc[i][j] = __builtin_amdgcn_mfma_f32_16x16x32_bf16(
                    af[i], bf[j], acc[i][j], 0, 0, 0);
    }
    qkv_epilogue(acc, which, n0, m0, wn, wm, l15, quad, Qb, Kb, Vt);
}

// ---------------------------------------------------------------------------
// Stage 2: causal flash attention, 32x32x16 swapped-QK^T (m214/T12).
// KVBLK=128 + XOR-slot LDS swizzle (unchanged from r4 — verified).
// ---------------------------------------------------------------------------
#define VXOR(d) ((((d) & 7) << 1) | (((d) >> 3) & 1))

__global__ __launch_bounds__(256, 2)
void attn(const u16* __restrict__ Qb, const u16* __restrict__ Kb,
          const u16* __restrict__ Vt, u16* __restrict__ Cx)
{
    __shared__ __align__(16) short Ks[128 * 64];     // [key][d-slot swz]
    __shared__ __align__(16) short Vs[64 * 128];     // [d][key-slot swz]

    const int ell = blockIdx.x;            // 0..511
    const int xcd = ell & 7;
    const int rest = ell >> 3;             // 0..63
    const int p = rest & 7;                // pair index 0..7
    const int bh = ((rest >> 3) << 3) | xcd;

    const int t = threadIdx.x;
    const int lane = t & 63;
    const int l31 = lane & 31;
    const int hi = lane >> 5;
    const int wave = t >> 6;
    const int koff = hi * 8;

    const u16* Qh = Qb + (size_t)bh * SEQ * HDIM;
    const u16* Kh = Kb + (size_t)bh * SEQ * HDIM;
    const u16* Vh = Vt + (size_t)bh * HDIM * SEQ;

    // staging coords: K rows 128 x 8 slots, V rows 64 x 16 slots
    const int krow = t >> 3;          // 0..31 (row within 32-group)
    const int kslot = t & 7;
    const int vrow = t >> 4;          // 0..15 (d within 16-group)
    const int vslot = t & 15;
    const int b = bh >> 4, h = bh & 15;

#pragma unroll 1
    for (int phase = 0; phase < 2; ++phase) {
        const int qt = phase ? p : (15 - p);   // long tile first
        const int q0w = qt * 128 + wave * 32;

        v8s qf[4];
#pragma unroll
        for (int dc = 0; dc < 4; ++dc)
            qf[dc] = *(const v8s*)
                &Qh[(size_t)(q0w + l31) * HDIM + dc * 16 + koff];

        v16f o0, o1;
#pragma unroll
        for (int r = 0; r < 16; ++r) { o0[r] = 0.f; o1[r] = 0.f; }
        float ls = 0.f;

        // prefetch kb=0 (128 keys: K 4x32 rows, V 4x16 d-rows)
        v8s pk[4], pv[4];
#pragma unroll
        for (int it = 0; it < 4; ++it)
            pk[it] = *(const v8s*)
                &Kh[(size_t)(it * 32 + krow) * HDIM + kslot * 8];
#pragma unroll
        for (int it = 0; it < 4; ++it)
            pv[it] = *(const v8s*)
                &Vh[(size_t)(it * 16 + vrow) * SEQ + vslot * 8];

#pragma unroll 1
        for (int kb = 0; kb <= qt; ++kb) {
            __syncthreads();
#pragma unroll
            for (int it = 0; it < 4; ++it) {
                int row = it * 32 + krow;
                *(v8s*)&Ks[row * 64 + ((kslot ^ (row & 7)) << 3)] = pk[it];
            }
#pragma unroll
            for (int it = 0; it < 4; ++it) {
                int d = it * 16 + vrow;
                *(v8s*)&Vs[d * 128 + ((vslot ^ VXOR(d)) << 3)] = pv[it];
            }
            __syncthreads();

            if (kb < qt) {  // prefetch next 128-key block, overlaps compute
                const int kn = (kb + 1) * 128;
#pragma unroll
                for (int it = 0; it < 4; ++it)
                    pk[it] = *(const v8s*)
                        &Kh[(size_t)(kn + it * 32 + krow) * HDIM + kslot * 8];
#pragma unroll
                for (int it = 0; it < 4; ++it)
                    pv[it] = *(const v8s*)
                        &Vh[(size_t)(it * 16 + vrow) * SEQ + kn + vslot * 8];
            }

#pragma unroll
            for (int k2 = 0; k2 < 2; ++k2) {
                const int kbase = kb * 128 + k2 * 64;
                if (kbase > q0w + 31) continue;   // wave-uniform skip
                const bool diag = (kbase + 63 > q0w);
                const int qrow = q0w + l31;

                // QK^T swapped: St[key][q], two 32-key subtiles
                v16f st0, st1;
#pragma unroll
                for (int r = 0; r < 16; ++r) { st0[r] = 0.f; st1[r] = 0.f; }
#pragma unroll
                for (int dc = 0; dc < 4; ++dc) {
                    const int ds = dc * 2 + hi;       // 16B d-slot
                    const int r0 = k2 * 64 + l31;
                    const int r1 = k2 * 64 + 32 + l31;
                    v8s kf0 = *(const v8s*)
                        &Ks[r0 * 64 + ((ds ^ (r0 & 7)) << 3)];
                    v8s kf1 = *(const v8s*)
                        &Ks[r1 * 64 + ((ds ^ (r1 & 7)) << 3)];
                    st0 = __builtin_amdgcn_mfma_f32_32x32x16_bf16(
                        kf0, qf[dc], st0, 0, 0, 0);
                    st1 = __builtin_amdgcn_mfma_f32_32x32x16_bf16(
                        kf1, qf[dc], st1, 0, 0, 0);
                }

                // softmax numerator (scores pre-scaled by 1/8*log2e in Q)
                v16f pe0, pe1;
                if (!diag) {
#pragma unroll
                    for (int r = 0; r < 16; ++r) {
                        pe0[r] = exp2f(st0[r]);
                        pe1[r] = exp2f(st1[r]);
                    }
                } else {
#pragma unroll
                    for (int r = 0; r < 16; ++r) {
                        int kl = kbase + (r & 3) + 8 * (r >> 2) + 4 * hi;
                        pe0[r] = (kl > qrow) ? 0.f : exp2f(st0[r]);
                        pe1[r] = (kl + 32 > qrow) ? 0.f : exp2f(st1[r]);
                    }
                }
#pragma unroll
                for (int r = 0; r < 16; ++r) ls += pe0[r] + pe1[r];

                // in-register P -> A-fragments (T12)
                v8s pa0 = build_pa(pe0[0], pe0[1], pe0[2], pe0[3],
                                   pe0[4], pe0[5], pe0[6], pe0[7]);
                v8s pa1 = build_pa(pe0[8], pe0[9], pe0[10], pe0[11],
                                   pe0[12], pe0[13], pe0[14], pe0[15]);
                v8s pa2 = build_pa(pe1[0], pe1[1], pe1[2], pe1[3],
                                   pe1[4], pe1[5], pe1[6], pe1[7]);
                v8s pa3 = build_pa(pe1[8], pe1[9], pe1[10], pe1[11],
                                   pe1[12], pe1[13], pe1[14], pe1[15]);

                // PV: O[q][d], two d-tiles (o0: d 0..31, o1: d 32..63)
#pragma unroll
                for (int kc = 0; kc < 4; ++kc) {
                    v8s pav = (kc == 0) ? pa0 : (kc == 1) ? pa1
                              : (kc == 2) ? pa2 : pa3;
                    const int ks = k2 * 8 + kc * 2 + hi;  // 16B key-slot
                    const int d0 = l31, d1 = 32 + l31;
                    v8s vf0 = *(const v8s*)
                        &Vs[d0 * 128 + ((ks ^ VXOR(d0)) << 3)];
                    v8s vf1 = *(const v8s*)
                        &Vs[d1 * 128 + ((ks ^ VXOR(d1)) << 3)];
                    o0 = __builtin_amdgcn_mfma_f32_32x32x16_bf16(
                        pav, vf0, o0, 0, 0, 0);
                    o1 = __builtin_amdgcn_mfma_f32_32x32x16_bf16(
                        pav, vf1, o1, 0, 0, 0);
                }
            }
        }

        // close row-sums (lane + partner half), normalize, store
        ls += __shfl_xor(ls, 32, 64);
        float inv = 1.f / ls;
#pragma unroll
        for (int r = 0; r < 16; ++r) {
            int m = (r & 3) + 8 * (r >> 2) + 4 * hi;
            float im = __shfl(inv, m, 64);
            size_t idx = ((size_t)(b * SEQ + q0w + m)) * DMODEL
                         + h * HDIM + l31;
            Cx[idx] = f2bf(o0[r] * im);
            Cx[idx + 32] = f2bf(o1[r] * im);
        }
    }
}

// ---------------------------------------------------------------------------
// Stage 3: out = Cx @ W_o + b_o. Both operands async, BK=64.
// ---------------------------------------------------------------------------
__global__ __launch_bounds__(256, 2)
void out_gemm(const u16* __restrict__ Cx, const u16* __restrict__ WoT,
              const float* __restrict__ bo, float* __restrict__ Y)
{
    __shared__ __align__(16) short As[128 * 64];
    __shared__ __align__(16) short Bs[128 * 64];

    const int n0 = blockIdx.x * 128;
    const int m0 = blockIdx.y * 128;
    const int t = threadIdx.x;
    const int lane = t & 63;
    const int l15 = lane & 15;
    const int quad = lane >> 4;
    const int wave = t >> 6;
    const int wm = (wave >> 1) * 64;
    const int wn = (wave & 1) * 64;
    const int srow = t >> 3;
    const int sc8 = (t & 7) * 8;

    v4f acc[4][4];
#pragma unroll
    for (int i = 0; i < 4; ++i)
#pragma unroll
        for (int j = 0; j < 4; ++j) acc[i][j] = {0.f, 0.f, 0.f, 0.f};

    for (int k0 = 0; k0 < DMODEL; k0 += 64) {
        __syncthreads();
#pragma unroll
        for (int c = 0; c < 4; ++c) {
            g2l16(&Cx[(size_t)(m0 + c * 32 + srow) * DMODEL + k0 + sc8],
                  &As[(c * 32 + srow) * 64 + sc8]);
            g2l16(&WoT[(size_t)(n0 + c * 32 + srow) * DMODEL + k0 + sc8],
                  &Bs[(c * 32 + srow) * 64 + sc8]);
        }
        __syncthreads();

#pragma unroll
        for (int kh = 0; kh < 2; ++kh) {
            v8s af[4], bf[4];
#pragma unroll
            for (int i = 0; i < 4; ++i)
                af[i] = *(const v8s*)
                    &As[(wm + i * 16 + l15) * 64 + kh * 32 + quad * 8];
#pragma unroll
            for (int j = 0; j < 4; ++j)
                bf[j] = *(const v8s*)
                    &Bs[(wn + j * 16 + l15) * 64 + kh * 32 + quad * 8];
#pragma unroll
            for (int i = 0; i < 4; ++i)
#pragma unroll
                for (int j = 0; j < 4; ++j)
                    acc[i][j] = __builtin_amdgcn_mfma_f32_16x16x32_bf16(
                        af[i], bf[j], acc[i][j], 0, 0, 0);
        }
    }

#pragma unroll
    for (int i = 0; i < 4; ++i)
#pragma unroll
        for (int j = 0; j < 4; ++j) {
            int col = n0 + wn + j * 16 + l15;
            float bias = bo[col];
#pragma unroll
            for (int r = 0; r < 4; ++r) {
                int m = m0 + wm + i * 16 + quad * 4 + r;
                Y[(size_t)m * DMODEL + col] = acc[i][j][r] + bias;
            }
        }
}

// ---------------------------------------------------------------------------
extern "C" void kernel_launch(void* const* d_in, const int* in_sizes, int n_in,
                              void* d_out, int out_size, void* d_ws,
                              size_t ws_size, hipStream_t stream)
{
    const float* x  = (const float*)d_in[0];
    const float* Wq = (const float*)d_in[1];
    const float* Wk = (const float*)d_in[2];
    const float* Wv = (const float*)d_in[3];
    const float* Wo = (const float*)d_in[4];
    const float* bo = (const float*)d_in[5];
    float* Y = (float*)d_out;

    const size_t per = (size_t)BATCH * NHEADS * SEQ * HDIM;  // 8M elems
    const size_t wsz = (size_t)DMODEL * DMODEL;              // 1M elems
    u16* base = (u16*)d_ws;

    if (ws_size >= (size_t)72 * 1024 * 1024) {
        u16* xb  = base;
        u16* Cx  = base;                 // aliases xb (dead after qkv)
        u16* Wt4 = base + per;           // 4 transposed weights
        u16* Qb  = base + per + 4 * wsz;
        u16* Kb  = Qb + per;
        u16* Vt  = Kb + per;

        prep<<<1024 + MTOT * DMODEL / (256 * 8), 256, 0, stream>>>(
            x, xb, Wq, Wk, Wv, Wo, Wt4);
        qkv_fast<<<dim3(DMODEL / 128, MTOT / 128, 3), 256, 0, stream>>>(
            xb, Wt4, Qb, Kb, Vt);
        attn<<<512, 256, 0, stream>>>(Qb, Kb, Vt, Cx);
        out_gemm<<<dim3(DMODEL / 128, MTOT / 128), 256, 0, stream>>>(
            Cx, Wt4 + 3 * wsz, bo, Y);
    } else {
        u16* Wt  = base;              // 3 weights [0,6MB)
        u16* Cx  = base;              // aliases Wt (dead after qkv)
        u16* Qb  = base + per;
        u16* WoT = base + per;        // aliases Qb after attn
        u16* Kb  = base + 2 * per;
        u16* Vt  = base + 3 * per;

        transpose_w<<<dim3(16, 16), 256, 0, stream>>>(Wq, Wt);
        transpose_w<<<dim3(16, 16), 256, 0, stream>>>(Wk, Wt + wsz);
        transpose_w<<<dim3(16, 16), 256, 0, stream>>>(Wv, Wt + 2 * wsz);
        qkv_slow<<<dim3(DMODEL / 128, MTOT / 128, 3), 256, 0, stream>>>(
            x, Wt, Qb, Kb, Vt);
        attn<<<512, 256, 0, stream>>>(Qb, Kb, Vt, Cx);
        transpose_w<<<dim3(16, 16), 256, 0, stream>>>(Wo, WoT);
        out_gemm<<<dim3(DMODEL / 128, MTOT / 128), 256, 0, stream>>>(
            Cx, WoT, bo, Y);
    }
}

// Round 7
// 261.206 us; speedup vs baseline: 1.1292x; 1.1292x over previous
//
#include <hip/hip_runtime.h>
#include <hip/hip_bf16.h>

#define NHEADS 16
#define HDIM 64
#define SEQ 2048
#define BATCH 4
#define DMODEL 1024
#define MTOT (BATCH * SEQ)

typedef short v8s __attribute__((ext_vector_type(8)));
typedef short v4s __attribute__((ext_vector_type(4)));
typedef float v4f __attribute__((ext_vector_type(4)));
typedef float v16f __attribute__((ext_vector_type(16)));
typedef unsigned int v4u __attribute__((ext_vector_type(4)));
typedef unsigned short u16;
typedef unsigned int u32;

__device__ __forceinline__ u16 f2bf(float f) {
    union { float f; unsigned u; } v; v.f = f;
    unsigned r = v.u + 0x7FFFu + ((v.u >> 16) & 1u);
    return (u16)(r >> 16);
}

// async global->LDS, 16B/lane; LDS dest = wave-uniform base + lane*16.
__device__ __forceinline__ void g2l16(const u16* g, short* l) {
    __builtin_amdgcn_global_load_lds(
        (const __attribute__((address_space(1))) u32*)g,
        (__attribute__((address_space(3))) u32*)l, 16, 0, 0);
}

// v_cvt_pk_bf16_f32: pack two f32 -> one u32 of 2 bf16 (lo=a, hi=b)
__device__ __forceinline__ unsigned pk_bf16(float a, float b) {
    unsigned r;
    asm("v_cvt_pk_bf16_f32 %0, %1, %2" : "=v"(r) : "v"(a), "v"(b));
    return r;
}
// v_permlane32_swap_b32: x[32..63] <-> y[0..31]
__device__ __forceinline__ void pl32swap(unsigned& x, unsigned& y) {
    asm("v_permlane32_swap_b32 %0, %1" : "+v"(x), "+v"(y));
}
// Build one PV A-fragment (16 keys) from 8 lane-local P values.
__device__ __forceinline__ v8s build_pa(float a0, float a1, float a2, float a3,
                                        float b0, float b1, float b2, float b3) {
    unsigned X  = pk_bf16(a0, a1);
    unsigned X2 = pk_bf16(a2, a3);
    unsigned Y  = pk_bf16(b0, b1);
    unsigned Y2 = pk_bf16(b2, b3);
    pl32swap(X, Y);
    pl32swap(X2, Y2);
    v4u w; w[0] = X; w[1] = X2; w[2] = Y; w[3] = Y2;
    return __builtin_bit_cast(v8s, w);
}

// ---------------------------------------------------------------------------
// Weight transpose body: src fp32 [k][n] -> dst bf16 [n][k].
// ---------------------------------------------------------------------------
__device__ __forceinline__ void transpose_body(
    const float* __restrict__ src, u16* __restrict__ dst, int k0, int n0)
{
    __shared__ __align__(8) short Ts[64 * 68];
    const int t = threadIdx.x;
    const int n4 = (t & 15) * 4, kl = t >> 4;
#pragma unroll
    for (int it = 0; it < 4; ++it) {
        int k = kl + 16 * it;
        v4f v = *(const v4f*)&src[(size_t)(k0 + k) * DMODEL + n0 + n4];
        v4s p;
#pragma unroll
        for (int e = 0; e < 4; ++e) p[e] = (short)f2bf(v[e]);
        *(v4s*)&Ts[k * 68 + n4] = p;
    }
    __syncthreads();
    const int nl = t >> 4, k4 = (t & 15) * 4;
#pragma unroll
    for (int it = 0; it < 4; ++it) {
        int n = nl + 16 * it;
        v4s o;
#pragma unroll
        for (int e = 0; e < 4; ++e) o[e] = Ts[(k4 + e) * 68 + n];
        *(v4s*)&dst[(size_t)(n0 + n) * DMODEL + k0 + k4] = o;
    }
}

__global__ __launch_bounds__(256)
void transpose_w(const float* __restrict__ src, u16* __restrict__ dst)
{
    transpose_body(src, dst, blockIdx.x * 64, blockIdx.y * 64);
}

// ---------------------------------------------------------------------------
// prep: fused {4x weight transpose} + {x fp32->bf16}. One dispatch (saved
// ~4us vs two in r4/r5 A/B).
// ---------------------------------------------------------------------------
__global__ __launch_bounds__(256)
void prep(const float* __restrict__ x, u16* __restrict__ xb,
          const float* __restrict__ s0, const float* __restrict__ s1,
          const float* __restrict__ s2, const float* __restrict__ s3,
          u16* __restrict__ wdst)
{
    const int blk = blockIdx.x;
    if (blk < 1024) {
        const int z = blk >> 8;
        const int rem = blk & 255;
        const float* src = (z == 0) ? s0 : (z == 1) ? s1 : (z == 2) ? s2 : s3;
        transpose_body(src, wdst + (size_t)z * DMODEL * DMODEL,
                       (rem & 15) * 64, (rem >> 4) * 64);
    } else {
        size_t i = ((size_t)(blk - 1024) * 256 + threadIdx.x) * 8;
        v4f a = *(const v4f*)&x[i];
        v4f b = *(const v4f*)&x[i + 4];
        v8s p;
#pragma unroll
        for (int e = 0; e < 4; ++e) p[e] = (short)f2bf(a[e]);
#pragma unroll
        for (int e = 0; e < 4; ++e) p[4 + e] = (short)f2bf(b[e]);
        *(v8s*)&xb[i] = p;
    }
}

// ---------------------------------------------------------------------------
// QKV epilogue. Q scale folds softmax 1/8 AND log2(e) (exp2 in attn).
// ---------------------------------------------------------------------------
#define QSCALE (0.125f * 1.44269504088896f)

__device__ __forceinline__ void qkv_epilogue(
    v4f (&acc)[4][4], int which, int n0, int m0, int wn, int wm,
    int l15, int quad, u16* Qb, u16* Kb, u16* Vt)
{
    if (which == 2) {
#pragma unroll
        for (int i = 0; i < 4; ++i)
#pragma unroll
            for (int j = 0; j < 4; ++j) {
                int col = n0 + wn + j * 16 + l15;
                int h = col >> 6, d = col & 63;
                int m = m0 + wm + i * 16 + quad * 4;
                int b = m >> 11, n = m & (SEQ - 1);
                v4s pv;
#pragma unroll
                for (int r = 0; r < 4; ++r) pv[r] = (short)f2bf(acc[i][j][r]);
                *(v4s*)&Vt[((size_t)(b * NHEADS + h) * HDIM + d) * SEQ + n] = pv;
            }
    } else {
        u16* Ob = (which == 0) ? Qb : Kb;
        const float scale = (which == 0) ? QSCALE : 1.0f;
#pragma unroll
        for (int i = 0; i < 4; ++i)
#pragma unroll
            for (int j = 0; j < 4; ++j) {
                int col = n0 + wn + j * 16 + l15;
                int h = col >> 6, d = col & 63;
#pragma unroll
                for (int r = 0; r < 4; ++r) {
                    int m = m0 + wm + i * 16 + quad * 4 + r;
                    int b = m >> 11, n = m & (SEQ - 1);
                    Ob[((size_t)(b * NHEADS + h) * SEQ + n) * HDIM + d] =
                        f2bf(acc[i][j][r] * scale);
                }
            }
    }
}

// ---------------------------------------------------------------------------
// qkv fast: BM=256 x BN=128, BK=64, 8 waves (4m x 2n, per-wave 64x64).
// Counted-vmcnt deep pipeline (T3+T4): triple-buffered LDS (144 KiB, 1
// block/CU), prefetch depth 2, ONE barrier + ONE vmcnt(6) per K-tile —
// never drains to 0 until the tail. T2 both-sides XOR slot swizzle
// (r2-verified: 0 bank conflicts). Grid 24x32 = 768 = 3 exact CU-rounds.
// z folded into x: which = bx>>3 (128-col tiles never straddle a 1024
// boundary since 1024 % 128 == 0).
// ---------------------------------------------------------------------------
#define QKV_ABUF (256 * 64)
#define QKV_BBUF (128 * 64)

__device__ __forceinline__ void qkv_stage(
    const u16* __restrict__ xb, const u16* __restrict__ W,
    int m0, int t, int s, short* As3, short* Bs3)
{
    const int srr = t >> 3;                      // 0..63
    const int scol = ((t & 7) ^ (srr & 7)) * 8;  // pre-swizzled global col
    short* A = As3 + (s % 3) * QKV_ABUF;
    short* B = Bs3 + (s % 3) * QKV_BBUF;
    const int k0 = s * 64;
#pragma unroll
    for (int c = 0; c < 4; ++c)
        g2l16(&xb[(size_t)(m0 + c * 64 + srr) * DMODEL + k0 + scol],
              &A[(c * 64 + srr) * 64 + (t & 7) * 8]);
#pragma unroll
    for (int c = 0; c < 2; ++c)
        g2l16(&W[(size_t)(c * 64 + srr) * DMODEL + k0 + scol],
              &B[(c * 64 + srr) * 64 + (t & 7) * 8]);
}

__global__ __launch_bounds__(512, 1)
void qkv_fast(const u16* __restrict__ xb, const u16* __restrict__ Wt,
              u16* __restrict__ Qb, u16* __restrict__ Kb, u16* __restrict__ Vt)
{
    __shared__ __align__(16) short As3[3 * QKV_ABUF];   // 96 KiB
    __shared__ __align__(16) short Bs3[3 * QKV_BBUF];   // 48 KiB

    const int bx = blockIdx.x;              // 0..23
    const int which = bx >> 3;              // 0..2
    const int n0 = (bx & 7) * 128;          // col within one weight
    const int m0 = blockIdx.y * 256;
    // W row base folded in: rows n0..n0+127 of weight `which`
    const u16* W = Wt + (size_t)which * DMODEL * DMODEL + (size_t)n0 * DMODEL;

    const int t = threadIdx.x;
    const int lane = t & 63;
    const int l15 = lane & 15;
    const int quad = lane >> 4;
    const int wave = t >> 6;                // 0..7
    const int wm = (wave >> 1) * 64;        // 0..192
    const int wn = (wave & 1) * 64;         // 0 or 64

    v4f acc[4][4];
#pragma unroll
    for (int i = 0; i < 4; ++i)
#pragma unroll
        for (int j = 0; j < 4; ++j) acc[i][j] = {0.f, 0.f, 0.f, 0.f};

    // prologue: tiles 0 and 1 in flight (12 outstanding vmem/wave)
    qkv_stage(xb, W, m0, t, 0, As3, Bs3);
    qkv_stage(xb, W, m0, t, 1, As3, Bs3);

#pragma unroll 1
    for (int tt = 0; tt < 16; ++tt) {
        // wait tile tt resident (oldest 6); tile tt+1's 6 stay in flight
        if (tt < 15) asm volatile("s_waitcnt vmcnt(6)" ::: "memory");
        else         asm volatile("s_waitcnt vmcnt(0)" ::: "memory");
        __builtin_amdgcn_sched_barrier(0);
        __syncthreads();   // all waves' tile-tt writes visible; buf (tt+2)%3
                           // (read at tt-1) free for reuse

        if (tt + 2 < 16) qkv_stage(xb, W, m0, t, tt + 2, As3, Bs3);

        const short* A = As3 + (tt % 3) * QKV_ABUF;
        const short* B = Bs3 + (tt % 3) * QKV_BBUF;
        v8s af[4][2], bf[4][2];
#pragma unroll
        for (int i = 0; i < 4; ++i)
#pragma unroll
            for (int kh = 0; kh < 2; ++kh)
                af[i][kh] = *(const v8s*)&A[(wm + i * 16 + l15) * 64 +
                                            (((kh * 4 + quad) ^ (l15 & 7)) << 3)];
#pragma unroll
        for (int j = 0; j < 4; ++j)
#pragma unroll
            for (int kh = 0; kh < 2; ++kh)
                bf[j][kh] = *(const v8s*)&B[(wn + j * 16 + l15) * 64 +
                                            (((kh * 4 + quad) ^ (l15 & 7)) << 3)];
        __builtin_amdgcn_s_setprio(1);
#pragma unroll
        for (int i = 0; i < 4; ++i)
#pragma unroll
            for (int j = 0; j < 4; ++j)
#pragma unroll
                for (int kh = 0; kh < 2; ++kh)
                    acc[i][j] = __builtin_amdgcn_mfma_f32_16x16x32_bf16(
                        af[i][kh], bf[j][kh], acc[i][j], 0, 0, 0);
        __builtin_amdgcn_s_setprio(0);
    }

    qkv_epilogue(acc, which, n0, m0, wn, wm, l15, quad, Qb, Kb, Vt);
}

// ---------------------------------------------------------------------------
// qkv fallback: A = x fp32 converted at staging. BK=32. (small-ws path)
// ---------------------------------------------------------------------------
__global__ __launch_bounds__(256, 2)
void qkv_slow(const float* __restrict__ x, const u16* __restrict__ Wt,
              u16* __restrict__ Qb, u16* __restrict__ Kb, u16* __restrict__ Vt)
{
    __shared__ __align__(16) short As[128 * 32];
    __shared__ __align__(16) short Bs[128 * 32];

    const int which = blockIdx.z;
    const u16* W = Wt + (size_t)which * DMODEL * DMODEL;

    const int n0 = blockIdx.x * 128;
    const int m0 = blockIdx.y * 128;
    const int t = threadIdx.x;
    const int lane = t & 63;
    const int l15 = lane & 15;
    const int quad = lane >> 4;
    const int wave = t >> 6;
    const int wm = (wave >> 1) * 64;
    const int wn = (wave & 1) * 64;
    const int srow = t >> 2;
    const int sc8 = (t & 3) * 8;

    v4f acc[4][4];
#pragma unroll
    for (int i = 0; i < 4; ++i)
#pragma unroll
        for (int j = 0; j < 4; ++j) acc[i][j] = {0.f, 0.f, 0.f, 0.f};

    for (int k0 = 0; k0 < DMODEL; k0 += 32) {
        __syncthreads();
        g2l16(&W[(size_t)(n0 + srow) * DMODEL + k0 + sc8], &Bs[srow * 32 + sc8]);
        g2l16(&W[(size_t)(n0 + 64 + srow) * DMODEL + k0 + sc8],
              &Bs[(64 + srow) * 32 + sc8]);
#pragma unroll
        for (int it = 0; it < 2; ++it) {
            int row = srow + 64 * it;
            const float* xp = &x[(size_t)(m0 + row) * DMODEL + k0 + sc8];
            v4f x0 = *(const v4f*)xp;
            v4f x1 = *(const v4f*)(xp + 4);
            v8s av;
#pragma unroll
            for (int e = 0; e < 4; ++e) av[e] = (short)f2bf(x0[e]);
#pragma unroll
            for (int e = 0; e < 4; ++e) av[4 + e] = (short)f2bf(x1[e]);
            *(v8s*)&As[row * 32 + sc8] = av;
        }
        __syncthreads();

        v8s af[4], bf[4];
#pragma unroll
        for (int i = 0; i < 4; ++i)
            af[i] = *(const v8s*)&As[(wm + i * 16 + l15) * 32 + quad * 8];
#pragma unroll
        for (int j = 0; j < 4; ++j)
            bf[j] = *(const v8s*)&Bs[(wn + j * 16 + l15) * 32 + quad * 8];
#pragma unroll
        for (int i = 0; i < 4; ++i)
#pragma unroll
            for (int j = 0; j < 4; ++j)
                acc[i][j] = __builtin_amdgcn_mfma_f32_16x16x32_bf16(
                    af[i], bf[j], acc[i][j], 0, 0, 0);
    }
    qkv_epilogue(acc, which, n0, m0, wn, wm, l15, quad, Qb, Kb, Vt);
}

// ---------------------------------------------------------------------------
// Stage 2: causal flash attention, 32x32x16 swapped-QK^T (m214/T12).
// KVBLK=128 + XOR-slot LDS swizzle (unchanged from r4 — verified).
// ---------------------------------------------------------------------------
#define VXOR(d) ((((d) & 7) << 1) | (((d) >> 3) & 1))

__global__ __launch_bounds__(256, 2)
void attn(const u16* __restrict__ Qb, const u16* __restrict__ Kb,
          const u16* __restrict__ Vt, u16* __restrict__ Cx)
{
    __shared__ __align__(16) short Ks[128 * 64];     // [key][d-slot swz]
    __shared__ __align__(16) short Vs[64 * 128];     // [d][key-slot swz]

    const int ell = blockIdx.x;            // 0..511
    const int xcd = ell & 7;
    const int rest = ell >> 3;             // 0..63
    const int p = rest & 7;                // pair index 0..7
    const int bh = ((rest >> 3) << 3) | xcd;

    const int t = threadIdx.x;
    const int lane = t & 63;
    const int l31 = lane & 31;
    const int hi = lane >> 5;
    const int wave = t >> 6;
    const int koff = hi * 8;

    const u16* Qh = Qb + (size_t)bh * SEQ * HDIM;
    const u16* Kh = Kb + (size_t)bh * SEQ * HDIM;
    const u16* Vh = Vt + (size_t)bh * HDIM * SEQ;

    // staging coords: K rows 128 x 8 slots, V rows 64 x 16 slots
    const int krow = t >> 3;          // 0..31 (row within 32-group)
    const int kslot = t & 7;
    const int vrow = t >> 4;          // 0..15 (d within 16-group)
    const int vslot = t & 15;
    const int b = bh >> 4, h = bh & 15;

#pragma unroll 1
    for (int phase = 0; phase < 2; ++phase) {
        const int qt = phase ? p : (15 - p);   // long tile first
        const int q0w = qt * 128 + wave * 32;

        v8s qf[4];
#pragma unroll
        for (int dc = 0; dc < 4; ++dc)
            qf[dc] = *(const v8s*)
                &Qh[(size_t)(q0w + l31) * HDIM + dc * 16 + koff];

        v16f o0, o1;
#pragma unroll
        for (int r = 0; r < 16; ++r) { o0[r] = 0.f; o1[r] = 0.f; }
        float ls = 0.f;

        // prefetch kb=0 (128 keys: K 4x32 rows, V 4x16 d-rows)
        v8s pk[4], pv[4];
#pragma unroll
        for (int it = 0; it < 4; ++it)
            pk[it] = *(const v8s*)
                &Kh[(size_t)(it * 32 + krow) * HDIM + kslot * 8];
#pragma unroll
        for (int it = 0; it < 4; ++it)
            pv[it] = *(const v8s*)
                &Vh[(size_t)(it * 16 + vrow) * SEQ + vslot * 8];

#pragma unroll 1
        for (int kb = 0; kb <= qt; ++kb) {
            __syncthreads();
#pragma unroll
            for (int it = 0; it < 4; ++it) {
                int row = it * 32 + krow;
                *(v8s*)&Ks[row * 64 + ((kslot ^ (row & 7)) << 3)] = pk[it];
            }
#pragma unroll
            for (int it = 0; it < 4; ++it) {
                int d = it * 16 + vrow;
                *(v8s*)&Vs[d * 128 + ((vslot ^ VXOR(d)) << 3)] = pv[it];
            }
            __syncthreads();

            if (kb < qt) {  // prefetch next 128-key block, overlaps compute
                const int kn = (kb + 1) * 128;
#pragma unroll
                for (int it = 0; it < 4; ++it)
                    pk[it] = *(const v8s*)
                        &Kh[(size_t)(kn + it * 32 + krow) * HDIM + kslot * 8];
#pragma unroll
                for (int it = 0; it < 4; ++it)
                    pv[it] = *(const v8s*)
                        &Vh[(size_t)(it * 16 + vrow) * SEQ + kn + vslot * 8];
            }

#pragma unroll
            for (int k2 = 0; k2 < 2; ++k2) {
                const int kbase = kb * 128 + k2 * 64;
                if (kbase > q0w + 31) continue;   // wave-uniform skip
                const bool diag = (kbase + 63 > q0w);
                const int qrow = q0w + l31;

                // QK^T swapped: St[key][q], two 32-key subtiles
                v16f st0, st1;
#pragma unroll
                for (int r = 0; r < 16; ++r) { st0[r] = 0.f; st1[r] = 0.f; }
#pragma unroll
                for (int dc = 0; dc < 4; ++dc) {
                    const int ds = dc * 2 + hi;       // 16B d-slot
                    const int r0 = k2 * 64 + l31;
                    const int r1 = k2 * 64 + 32 + l31;
                    v8s kf0 = *(const v8s*)
                        &Ks[r0 * 64 + ((ds ^ (r0 & 7)) << 3)];
                    v8s kf1 = *(const v8s*)
                        &Ks[r1 * 64 + ((ds ^ (r1 & 7)) << 3)];
                    st0 = __builtin_amdgcn_mfma_f32_32x32x16_bf16(
                        kf0, qf[dc], st0, 0, 0, 0);
                    st1 = __builtin_amdgcn_mfma_f32_32x32x16_bf16(
                        kf1, qf[dc], st1, 0, 0, 0);
                }

                // softmax numerator (scores pre-scaled by 1/8*log2e in Q)
                v16f pe0, pe1;
                if (!diag) {
#pragma unroll
                    for (int r = 0; r < 16; ++r) {
                        pe0[r] = exp2f(st0[r]);
                        pe1[r] = exp2f(st1[r]);
                    }
                } else {
#pragma unroll
                    for (int r = 0; r < 16; ++r) {
                        int kl = kbase + (r & 3) + 8 * (r >> 2) + 4 * hi;
                        pe0[r] = (kl > qrow) ? 0.f : exp2f(st0[r]);
                        pe1[r] = (kl + 32 > qrow) ? 0.f : exp2f(st1[r]);
                    }
                }
#pragma unroll
                for (int r = 0; r < 16; ++r) ls += pe0[r] + pe1[r];

                // in-register P -> A-fragments (T12)
                v8s pa0 = build_pa(pe0[0], pe0[1], pe0[2], pe0[3],
                                   pe0[4], pe0[5], pe0[6], pe0[7]);
                v8s pa1 = build_pa(pe0[8], pe0[9], pe0[10], pe0[11],
                                   pe0[12], pe0[13], pe0[14], pe0[15]);
                v8s pa2 = build_pa(pe1[0], pe1[1], pe1[2], pe1[3],
                                   pe1[4], pe1[5], pe1[6], pe1[7]);
                v8s pa3 = build_pa(pe1[8], pe1[9], pe1[10], pe1[11],
                                   pe1[12], pe1[13], pe1[14], pe1[15]);

                // PV: O[q][d], two d-tiles (o0: d 0..31, o1: d 32..63)
#pragma unroll
                for (int kc = 0; kc < 4; ++kc) {
                    v8s pav = (kc == 0) ? pa0 : (kc == 1) ? pa1
                              : (kc == 2) ? pa2 : pa3;
                    const int ks = k2 * 8 + kc * 2 + hi;  // 16B key-slot
                    const int d0 = l31, d1 = 32 + l31;
                    v8s vf0 = *(const v8s*)
                        &Vs[d0 * 128 + ((ks ^ VXOR(d0)) << 3)];
                    v8s vf1 = *(const v8s*)
                        &Vs[d1 * 128 + ((ks ^ VXOR(d1)) << 3)];
                    o0 = __builtin_amdgcn_mfma_f32_32x32x16_bf16(
                        pav, vf0, o0, 0, 0, 0);
                    o1 = __builtin_amdgcn_mfma_f32_32x32x16_bf16(
                        pav, vf1, o1, 0, 0, 0);
                }
            }
        }

        // close row-sums (lane + partner half), normalize, store
        ls += __shfl_xor(ls, 32, 64);
        float inv = 1.f / ls;
#pragma unroll
        for (int r = 0; r < 16; ++r) {
            int m = (r & 3) + 8 * (r >> 2) + 4 * hi;
            float im = __shfl(inv, m, 64);
            size_t idx = ((size_t)(b * SEQ + q0w + m)) * DMODEL
                         + h * HDIM + l31;
            Cx[idx] = f2bf(o0[r] * im);
            Cx[idx + 32] = f2bf(o1[r] * im);
        }
    }
}

// ---------------------------------------------------------------------------
// Stage 3: out = Cx @ W_o + b_o. Both operands async, BK=64.
// ---------------------------------------------------------------------------
__global__ __launch_bounds__(256, 2)
void out_gemm(const u16* __restrict__ Cx, const u16* __restrict__ WoT,
              const float* __restrict__ bo, float* __restrict__ Y)
{
    __shared__ __align__(16) short As[128 * 64];
    __shared__ __align__(16) short Bs[128 * 64];

    const int n0 = blockIdx.x * 128;
    const int m0 = blockIdx.y * 128;
    const int t = threadIdx.x;
    const int lane = t & 63;
    const int l15 = lane & 15;
    const int quad = lane >> 4;
    const int wave = t >> 6;
    const int wm = (wave >> 1) * 64;
    const int wn = (wave & 1) * 64;
    const int srow = t >> 3;
    const int sc8 = (t & 7) * 8;

    v4f acc[4][4];
#pragma unroll
    for (int i = 0; i < 4; ++i)
#pragma unroll
        for (int j = 0; j < 4; ++j) acc[i][j] = {0.f, 0.f, 0.f, 0.f};

    for (int k0 = 0; k0 < DMODEL; k0 += 64) {
        __syncthreads();
#pragma unroll
        for (int c = 0; c < 4; ++c) {
            g2l16(&Cx[(size_t)(m0 + c * 32 + srow) * DMODEL + k0 + sc8],
                  &As[(c * 32 + srow) * 64 + sc8]);
            g2l16(&WoT[(size_t)(n0 + c * 32 + srow) * DMODEL + k0 + sc8],
                  &Bs[(c * 32 + srow) * 64 + sc8]);
        }
        __syncthreads();

#pragma unroll
        for (int kh = 0; kh < 2; ++kh) {
            v8s af[4], bf[4];
#pragma unroll
            for (int i = 0; i < 4; ++i)
                af[i] = *(const v8s*)
                    &As[(wm + i * 16 + l15) * 64 + kh * 32 + quad * 8];
#pragma unroll
            for (int j = 0; j < 4; ++j)
                bf[j] = *(const v8s*)
                    &Bs[(wn + j * 16 + l15) * 64 + kh * 32 + quad * 8];
#pragma unroll
            for (int i = 0; i < 4; ++i)
#pragma unroll
                for (int j = 0; j < 4; ++j)
                    acc[i][j] = __builtin_amdgcn_mfma_f32_16x16x32_bf16(
                        af[i], bf[j], acc[i][j], 0, 0, 0);
        }
    }

#pragma unroll
    for (int i = 0; i < 4; ++i)
#pragma unroll
        for (int j = 0; j < 4; ++j) {
            int col = n0 + wn + j * 16 + l15;
            float bias = bo[col];
#pragma unroll
            for (int r = 0; r < 4; ++r) {
                int m = m0 + wm + i * 16 + quad * 4 + r;
                Y[(size_t)m * DMODEL + col] = acc[i][j][r] + bias;
            }
        }
}

// ---------------------------------------------------------------------------
extern "C" void kernel_launch(void* const* d_in, const int* in_sizes, int n_in,
                              void* d_out, int out_size, void* d_ws,
                              size_t ws_size, hipStream_t stream)
{
    const float* x  = (const float*)d_in[0];
    const float* Wq = (const float*)d_in[1];
    const float* Wk = (const float*)d_in[2];
    const float* Wv = (const float*)d_in[3];
    const float* Wo = (const float*)d_in[4];
    const float* bo = (const float*)d_in[5];
    float* Y = (float*)d_out;

    const size_t per = (size_t)BATCH * NHEADS * SEQ * HDIM;  // 8M elems
    const size_t wsz = (size_t)DMODEL * DMODEL;              // 1M elems
    u16* base = (u16*)d_ws;

    if (ws_size >= (size_t)72 * 1024 * 1024) {
        u16* xb  = base;
        u16* Cx  = base;                 // aliases xb (dead after qkv)
        u16* Wt4 = base + per;           // 4 transposed weights
        u16* Qb  = base + per + 4 * wsz;
        u16* Kb  = Qb + per;
        u16* Vt  = Kb + per;

        prep<<<1024 + MTOT * DMODEL / (256 * 8), 256, 0, stream>>>(
            x, xb, Wq, Wk, Wv, Wo, Wt4);
        qkv_fast<<<dim3(24, MTOT / 256), 512, 0, stream>>>(
            xb, Wt4, Qb, Kb, Vt);
        attn<<<512, 256, 0, stream>>>(Qb, Kb, Vt, Cx);
        out_gemm<<<dim3(DMODEL / 128, MTOT / 128), 256, 0, stream>>>(
            Cx, Wt4 + 3 * wsz, bo, Y);
    } else {
        u16* Wt  = base;              // 3 weights [0,6MB)
        u16* Cx  = base;              // aliases Wt (dead after qkv)
        u16* Qb  = base + per;
        u16* WoT = base + per;        // aliases Qb after attn
        u16* Kb  = base + 2 * per;
        u16* Vt  = base + 3 * per;

        transpose_w<<<dim3(16, 16), 256, 0, stream>>>(Wq, Wt);
        transpose_w<<<dim3(16, 16), 256, 0, stream>>>(Wk, Wt + wsz);
        transpose_w<<<dim3(16, 16), 256, 0, stream>>>(Wv, Wt + 2 * wsz);
        qkv_slow<<<dim3(DMODEL / 128, MTOT / 128, 3), 256, 0, stream>>>(
            x, Wt, Qb, Kb, Vt);
        attn<<<512, 256, 0, stream>>>(Qb, Kb, Vt, Cx);
        transpose_w<<<dim3(16, 16), 256, 0, stream>>>(Wo, WoT);
        out_gemm<<<dim3(DMODEL / 128, MTOT / 128), 256, 0, stream>>>(
            Cx, WoT, bo, Y);
    }
}

// Round 8
// 259.711 us; speedup vs baseline: 1.1357x; 1.0058x over previous
//
#include <hip/hip_runtime.h>
#include <hip/hip_bf16.h>

#define NHEADS 16
#define HDIM 64
#define SEQ 2048
#define BATCH 4
#define DMODEL 1024
#define MTOT (BATCH * SEQ)

typedef short v8s __attribute__((ext_vector_type(8)));
typedef short v4s __attribute__((ext_vector_type(4)));
typedef float v4f __attribute__((ext_vector_type(4)));
typedef float v16f __attribute__((ext_vector_type(16)));
typedef unsigned int v4u __attribute__((ext_vector_type(4)));
typedef unsigned short u16;
typedef unsigned int u32;

__device__ __forceinline__ u16 f2bf(float f) {
    union { float f; unsigned u; } v; v.f = f;
    unsigned r = v.u + 0x7FFFu + ((v.u >> 16) & 1u);
    return (u16)(r >> 16);
}

// async global->LDS, 16B/lane; LDS dest = wave-uniform base + lane*16.
__device__ __forceinline__ void g2l16(const u16* g, short* l) {
    __builtin_amdgcn_global_load_lds(
        (const __attribute__((address_space(1))) u32*)g,
        (__attribute__((address_space(3))) u32*)l, 16, 0, 0);
}

// v_cvt_pk_bf16_f32: pack two f32 -> one u32 of 2 bf16 (lo=a, hi=b)
__device__ __forceinline__ unsigned pk_bf16(float a, float b) {
    unsigned r;
    asm("v_cvt_pk_bf16_f32 %0, %1, %2" : "=v"(r) : "v"(a), "v"(b));
    return r;
}
// v_permlane32_swap_b32: x[32..63] <-> y[0..31]
__device__ __forceinline__ void pl32swap(unsigned& x, unsigned& y) {
    asm("v_permlane32_swap_b32 %0, %1" : "+v"(x), "+v"(y));
}
// Build one PV A-fragment (16 keys) from 8 lane-local P values.
__device__ __forceinline__ v8s build_pa(float a0, float a1, float a2, float a3,
                                        float b0, float b1, float b2, float b3) {
    unsigned X  = pk_bf16(a0, a1);
    unsigned X2 = pk_bf16(a2, a3);
    unsigned Y  = pk_bf16(b0, b1);
    unsigned Y2 = pk_bf16(b2, b3);
    pl32swap(X, Y);
    pl32swap(X2, Y2);
    v4u w; w[0] = X; w[1] = X2; w[2] = Y; w[3] = Y2;
    return __builtin_bit_cast(v8s, w);
}

// ---------------------------------------------------------------------------
// Weight transpose body: src fp32 [k][n] -> dst bf16 [n][k].
// ---------------------------------------------------------------------------
__device__ __forceinline__ void transpose_body(
    const float* __restrict__ src, u16* __restrict__ dst, int k0, int n0)
{
    __shared__ __align__(8) short Ts[64 * 68];
    const int t = threadIdx.x;
    const int n4 = (t & 15) * 4, kl = t >> 4;
#pragma unroll
    for (int it = 0; it < 4; ++it) {
        int k = kl + 16 * it;
        v4f v = *(const v4f*)&src[(size_t)(k0 + k) * DMODEL + n0 + n4];
        v4s p;
#pragma unroll
        for (int e = 0; e < 4; ++e) p[e] = (short)f2bf(v[e]);
        *(v4s*)&Ts[k * 68 + n4] = p;
    }
    __syncthreads();
    const int nl = t >> 4, k4 = (t & 15) * 4;
#pragma unroll
    for (int it = 0; it < 4; ++it) {
        int n = nl + 16 * it;
        v4s o;
#pragma unroll
        for (int e = 0; e < 4; ++e) o[e] = Ts[(k4 + e) * 68 + n];
        *(v4s*)&dst[(size_t)(n0 + n) * DMODEL + k0 + k4] = o;
    }
}

__global__ __launch_bounds__(256)
void transpose_w(const float* __restrict__ src, u16* __restrict__ dst)
{
    transpose_body(src, dst, blockIdx.x * 64, blockIdx.y * 64);
}

// ---------------------------------------------------------------------------
// prep: fused {4x weight transpose} + {x fp32->bf16}. One dispatch (saved
// ~4us vs two in r4/r5 A/B).
// ---------------------------------------------------------------------------
__global__ __launch_bounds__(256)
void prep(const float* __restrict__ x, u16* __restrict__ xb,
          const float* __restrict__ s0, const float* __restrict__ s1,
          const float* __restrict__ s2, const float* __restrict__ s3,
          u16* __restrict__ wdst)
{
    const int blk = blockIdx.x;
    if (blk < 1024) {
        const int z = blk >> 8;
        const int rem = blk & 255;
        const float* src = (z == 0) ? s0 : (z == 1) ? s1 : (z == 2) ? s2 : s3;
        transpose_body(src, wdst + (size_t)z * DMODEL * DMODEL,
                       (rem & 15) * 64, (rem >> 4) * 64);
    } else {
        size_t i = ((size_t)(blk - 1024) * 256 + threadIdx.x) * 8;
        v4f a = *(const v4f*)&x[i];
        v4f b = *(const v4f*)&x[i + 4];
        v8s p;
#pragma unroll
        for (int e = 0; e < 4; ++e) p[e] = (short)f2bf(a[e]);
#pragma unroll
        for (int e = 0; e < 4; ++e) p[4 + e] = (short)f2bf(b[e]);
        *(v8s*)&xb[i] = p;
    }
}

// ---------------------------------------------------------------------------
// QKV epilogue. Q scale folds softmax 1/8 AND log2(e) (exp2 in attn).
// ---------------------------------------------------------------------------
#define QSCALE (0.125f * 1.44269504088896f)

__device__ __forceinline__ void qkv_epilogue(
    v4f (&acc)[4][4], int which, int n0, int m0, int wn, int wm,
    int l15, int quad, u16* Qb, u16* Kb, u16* Vt)
{
    if (which == 2) {
#pragma unroll
        for (int i = 0; i < 4; ++i)
#pragma unroll
            for (int j = 0; j < 4; ++j) {
                int col = n0 + wn + j * 16 + l15;
                int h = col >> 6, d = col & 63;
                int m = m0 + wm + i * 16 + quad * 4;
                int b = m >> 11, n = m & (SEQ - 1);
                v4s pv;
#pragma unroll
                for (int r = 0; r < 4; ++r) pv[r] = (short)f2bf(acc[i][j][r]);
                *(v4s*)&Vt[((size_t)(b * NHEADS + h) * HDIM + d) * SEQ + n] = pv;
            }
    } else {
        u16* Ob = (which == 0) ? Qb : Kb;
        const float scale = (which == 0) ? QSCALE : 1.0f;
#pragma unroll
        for (int i = 0; i < 4; ++i)
#pragma unroll
            for (int j = 0; j < 4; ++j) {
                int col = n0 + wn + j * 16 + l15;
                int h = col >> 6, d = col & 63;
#pragma unroll
                for (int r = 0; r < 4; ++r) {
                    int m = m0 + wm + i * 16 + quad * 4 + r;
                    int b = m >> 11, n = m & (SEQ - 1);
                    Ob[((size_t)(b * NHEADS + h) * SEQ + n) * HDIM + d] =
                        f2bf(acc[i][j][r] * scale);
                }
            }
    }
}

// ---------------------------------------------------------------------------
// qkv fast: BM=256 x BN=128, BK=64, 8 waves (4m x 2n, per-wave 64x64).
// Counted-vmcnt deep pipeline (T3+T4), triple-buffered LDS, prefetch depth 2.
// r8 fix: RAW s_barrier instead of __syncthreads() — __syncthreads emits
// s_waitcnt vmcnt(0) before s_barrier (m97 drain), which made r7's counted
// vmcnt(6) dead code and degraded the loop to the drain-0 2-phase (644 TF,
// matching m230's 2ph band). With raw barriers the vmcnt(6) is live: 6 loads
// (next tile) stay in flight across every barrier (T4, m218: +38-73%).
// Safety: a wave reaches tile-tt's barrier only after consuming its
// tile-(tt-1) ds_reads, so buffer (tt+2)%3 == (tt-1)%3 is read-complete
// before the post-barrier staging writes to it. sched_barrier(0) on both
// sides of s_barrier pins ds_read/stage code motion (rule #18).
// ---------------------------------------------------------------------------
#define QKV_ABUF (256 * 64)
#define QKV_BBUF (128 * 64)

__device__ __forceinline__ void qkv_stage(
    const u16* __restrict__ xb, const u16* __restrict__ W,
    int m0, int t, int s, short* As3, short* Bs3)
{
    const int srr = t >> 3;                      // 0..63
    const int scol = ((t & 7) ^ (srr & 7)) * 8;  // pre-swizzled global col
    short* A = As3 + (s % 3) * QKV_ABUF;
    short* B = Bs3 + (s % 3) * QKV_BBUF;
    const int k0 = s * 64;
#pragma unroll
    for (int c = 0; c < 4; ++c)
        g2l16(&xb[(size_t)(m0 + c * 64 + srr) * DMODEL + k0 + scol],
              &A[(c * 64 + srr) * 64 + (t & 7) * 8]);
#pragma unroll
    for (int c = 0; c < 2; ++c)
        g2l16(&W[(size_t)(c * 64 + srr) * DMODEL + k0 + scol],
              &B[(c * 64 + srr) * 64 + (t & 7) * 8]);
}

__global__ __launch_bounds__(512, 1)
void qkv_fast(const u16* __restrict__ xb, const u16* __restrict__ Wt,
              u16* __restrict__ Qb, u16* __restrict__ Kb, u16* __restrict__ Vt)
{
    __shared__ __align__(16) short As3[3 * QKV_ABUF];   // 96 KiB
    __shared__ __align__(16) short Bs3[3 * QKV_BBUF];   // 48 KiB

    const int bx = blockIdx.x;              // 0..23
    const int which = bx >> 3;              // 0..2
    const int n0 = (bx & 7) * 128;          // col within one weight
    const int m0 = blockIdx.y * 256;
    const u16* W = Wt + (size_t)which * DMODEL * DMODEL + (size_t)n0 * DMODEL;

    const int t = threadIdx.x;
    const int lane = t & 63;
    const int l15 = lane & 15;
    const int quad = lane >> 4;
    const int wave = t >> 6;                // 0..7
    const int wm = (wave >> 1) * 64;        // 0..192
    const int wn = (wave & 1) * 64;         // 0 or 64

    v4f acc[4][4];
#pragma unroll
    for (int i = 0; i < 4; ++i)
#pragma unroll
        for (int j = 0; j < 4; ++j) acc[i][j] = {0.f, 0.f, 0.f, 0.f};

    // prologue: tiles 0 and 1 in flight (12 outstanding vmem/wave)
    qkv_stage(xb, W, m0, t, 0, As3, Bs3);
    qkv_stage(xb, W, m0, t, 1, As3, Bs3);

#pragma unroll 1
    for (int tt = 0; tt < 16; ++tt) {
        // wait tile tt resident (oldest 6); tile tt+1's 6 STAY in flight
        if (tt < 15) asm volatile("s_waitcnt vmcnt(6)" ::: "memory");
        else         asm volatile("s_waitcnt vmcnt(0)" ::: "memory");
        __builtin_amdgcn_sched_barrier(0);
        __builtin_amdgcn_s_barrier();          // raw: no vmcnt(0) drain
        __builtin_amdgcn_sched_barrier(0);

        if (tt + 2 < 16) qkv_stage(xb, W, m0, t, tt + 2, As3, Bs3);

        const short* A = As3 + (tt % 3) * QKV_ABUF;
        const short* B = Bs3 + (tt % 3) * QKV_BBUF;
        v8s af[4][2], bf[4][2];
#pragma unroll
        for (int i = 0; i < 4; ++i)
#pragma unroll
            for (int kh = 0; kh < 2; ++kh)
                af[i][kh] = *(const v8s*)&A[(wm + i * 16 + l15) * 64 +
                                            (((kh * 4 + quad) ^ (l15 & 7)) << 3)];
#pragma unroll
        for (int j = 0; j < 4; ++j)
#pragma unroll
            for (int kh = 0; kh < 2; ++kh)
                bf[j][kh] = *(const v8s*)&B[(wn + j * 16 + l15) * 64 +
                                            (((kh * 4 + quad) ^ (l15 & 7)) << 3)];
        __builtin_amdgcn_s_setprio(1);
#pragma unroll
        for (int i = 0; i < 4; ++i)
#pragma unroll
            for (int j = 0; j < 4; ++j)
#pragma unroll
                for (int kh = 0; kh < 2; ++kh)
                    acc[i][j] = __builtin_amdgcn_mfma_f32_16x16x32_bf16(
                        af[i][kh], bf[j][kh], acc[i][j], 0, 0, 0);
        __builtin_amdgcn_s_setprio(0);
    }

    qkv_epilogue(acc, which, n0, m0, wn, wm, l15, quad, Qb, Kb, Vt);
}

// ---------------------------------------------------------------------------
// qkv fallback: A = x fp32 converted at staging. BK=32. (small-ws path)
// ---------------------------------------------------------------------------
__global__ __launch_bounds__(256, 2)
void qkv_slow(const float* __restrict__ x, const u16* __restrict__ Wt,
              u16* __restrict__ Qb, u16* __restrict__ Kb, u16* __restrict__ Vt)
{
    __shared__ __align__(16) short As[128 * 32];
    __shared__ __align__(16) short Bs[128 * 32];

    const int which = blockIdx.z;
    const u16* W = Wt + (size_t)which * DMODEL * DMODEL;

    const int n0 = blockIdx.x * 128;
    const int m0 = blockIdx.y * 128;
    const int t = threadIdx.x;
    const int lane = t & 63;
    const int l15 = lane & 15;
    const int quad = lane >> 4;
    const int wave = t >> 6;
    const int wm = (wave >> 1) * 64;
    const int wn = (wave & 1) * 64;
    const int srow = t >> 2;
    const int sc8 = (t & 3) * 8;

    v4f acc[4][4];
#pragma unroll
    for (int i = 0; i < 4; ++i)
#pragma unroll
        for (int j = 0; j < 4; ++j) acc[i][j] = {0.f, 0.f, 0.f, 0.f};

    for (int k0 = 0; k0 < DMODEL; k0 += 32) {
        __syncthreads();
        g2l16(&W[(size_t)(n0 + srow) * DMODEL + k0 + sc8], &Bs[srow * 32 + sc8]);
        g2l16(&W[(size_t)(n0 + 64 + srow) * DMODEL + k0 + sc8],
              &Bs[(64 + srow) * 32 + sc8]);
#pragma unroll
        for (int it = 0; it < 2; ++it) {
            int row = srow + 64 * it;
            const float* xp = &x[(size_t)(m0 + row) * DMODEL + k0 + sc8];
            v4f x0 = *(const v4f*)xp;
            v4f x1 = *(const v4f*)(xp + 4);
            v8s av;
#pragma unroll
            for (int e = 0; e < 4; ++e) av[e] = (short)f2bf(x0[e]);
#pragma unroll
            for (int e = 0; e < 4; ++e) av[4 + e] = (short)f2bf(x1[e]);
            *(v8s*)&As[row * 32 + sc8] = av;
        }
        __syncthreads();

        v8s af[4], bf[4];
#pragma unroll
        for (int i = 0; i < 4; ++i)
            af[i] = *(const v8s*)&As[(wm + i * 16 + l15) * 32 + quad * 8];
#pragma unroll
        for (int j = 0; j < 4; ++j)
            bf[j] = *(const v8s*)&Bs[(wn + j * 16 + l15) * 32 + quad * 8];
#pragma unroll
        for (int i = 0; i < 4; ++i)
#pragma unroll
            for (int j = 0; j < 4; ++j)
                acc[i][j] = __builtin_amdgcn_mfma_f32_16x16x32_bf16(
                    af[i], bf[j], acc[i][j], 0, 0, 0);
    }
    qkv_epilogue(acc, which, n0, m0, wn, wm, l15, quad, Qb, Kb, Vt);
}

// ---------------------------------------------------------------------------
// Stage 2: causal flash attention, 32x32x16 swapped-QK^T (m214/T12).
// KVBLK=128 + XOR-slot LDS swizzle (unchanged from r4 — verified).
// ---------------------------------------------------------------------------
#define VXOR(d) ((((d) & 7) << 1) | (((d) >> 3) & 1))

__global__ __launch_bounds__(256, 2)
void attn(const u16* __restrict__ Qb, const u16* __restrict__ Kb,
          const u16* __restrict__ Vt, u16* __restrict__ Cx)
{
    __shared__ __align__(16) short Ks[128 * 64];     // [key][d-slot swz]
    __shared__ __align__(16) short Vs[64 * 128];     // [d][key-slot swz]

    const int ell = blockIdx.x;            // 0..511
    const int xcd = ell & 7;
    const int rest = ell >> 3;             // 0..63
    const int p = rest & 7;                // pair index 0..7
    const int bh = ((rest >> 3) << 3) | xcd;

    const int t = threadIdx.x;
    const int lane = t & 63;
    const int l31 = lane & 31;
    const int hi = lane >> 5;
    const int wave = t >> 6;
    const int koff = hi * 8;

    const u16* Qh = Qb + (size_t)bh * SEQ * HDIM;
    const u16* Kh = Kb + (size_t)bh * SEQ * HDIM;
    const u16* Vh = Vt + (size_t)bh * HDIM * SEQ;

    // staging coords: K rows 128 x 8 slots, V rows 64 x 16 slots
    const int krow = t >> 3;          // 0..31 (row within 32-group)
    const int kslot = t & 7;
    const int vrow = t >> 4;          // 0..15 (d within 16-group)
    const int vslot = t & 15;
    const int b = bh >> 4, h = bh & 15;

#pragma unroll 1
    for (int phase = 0; phase < 2; ++phase) {
        const int qt = phase ? p : (15 - p);   // long tile first
        const int q0w = qt * 128 + wave * 32;

        v8s qf[4];
#pragma unroll
        for (int dc = 0; dc < 4; ++dc)
            qf[dc] = *(const v8s*)
                &Qh[(size_t)(q0w + l31) * HDIM + dc * 16 + koff];

        v16f o0, o1;
#pragma unroll
        for (int r = 0; r < 16; ++r) { o0[r] = 0.f; o1[r] = 0.f; }
        float ls = 0.f;

        // prefetch kb=0 (128 keys: K 4x32 rows, V 4x16 d-rows)
        v8s pk[4], pv[4];
#pragma unroll
        for (int it = 0; it < 4; ++it)
            pk[it] = *(const v8s*)
                &Kh[(size_t)(it * 32 + krow) * HDIM + kslot * 8];
#pragma unroll
        for (int it = 0; it < 4; ++it)
            pv[it] = *(const v8s*)
                &Vh[(size_t)(it * 16 + vrow) * SEQ + vslot * 8];

#pragma unroll 1
        for (int kb = 0; kb <= qt; ++kb) {
            __syncthreads();
#pragma unroll
            for (int it = 0; it < 4; ++it) {
                int row = it * 32 + krow;
                *(v8s*)&Ks[row * 64 + ((kslot ^ (row & 7)) << 3)] = pk[it];
            }
#pragma unroll
            for (int it = 0; it < 4; ++it) {
                int d = it * 16 + vrow;
                *(v8s*)&Vs[d * 128 + ((vslot ^ VXOR(d)) << 3)] = pv[it];
            }
            __syncthreads();

            if (kb < qt) {  // prefetch next 128-key block, overlaps compute
                const int kn = (kb + 1) * 128;
#pragma unroll
                for (int it = 0; it < 4; ++it)
                    pk[it] = *(const v8s*)
                        &Kh[(size_t)(kn + it * 32 + krow) * HDIM + kslot * 8];
#pragma unroll
                for (int it = 0; it < 4; ++it)
                    pv[it] = *(const v8s*)
                        &Vh[(size_t)(it * 16 + vrow) * SEQ + kn + vslot * 8];
            }

#pragma unroll
            for (int k2 = 0; k2 < 2; ++k2) {
                const int kbase = kb * 128 + k2 * 64;
                if (kbase > q0w + 31) continue;   // wave-uniform skip
                const bool diag = (kbase + 63 > q0w);
                const int qrow = q0w + l31;

                // QK^T swapped: St[key][q], two 32-key subtiles
                v16f st0, st1;
#pragma unroll
                for (int r = 0; r < 16; ++r) { st0[r] = 0.f; st1[r] = 0.f; }
#pragma unroll
                for (int dc = 0; dc < 4; ++dc) {
                    const int ds = dc * 2 + hi;       // 16B d-slot
                    const int r0 = k2 * 64 + l31;
                    const int r1 = k2 * 64 + 32 + l31;
                    v8s kf0 = *(const v8s*)
                        &Ks[r0 * 64 + ((ds ^ (r0 & 7)) << 3)];
                    v8s kf1 = *(const v8s*)
                        &Ks[r1 * 64 + ((ds ^ (r1 & 7)) << 3)];
                    st0 = __builtin_amdgcn_mfma_f32_32x32x16_bf16(
                        kf0, qf[dc], st0, 0, 0, 0);
                    st1 = __builtin_amdgcn_mfma_f32_32x32x16_bf16(
                        kf1, qf[dc], st1, 0, 0, 0);
                }

                // softmax numerator (scores pre-scaled by 1/8*log2e in Q)
                v16f pe0, pe1;
                if (!diag) {
#pragma unroll
                    for (int r = 0; r < 16; ++r) {
                        pe0[r] = exp2f(st0[r]);
                        pe1[r] = exp2f(st1[r]);
                    }
                } else {
#pragma unroll
                    for (int r = 0; r < 16; ++r) {
                        int kl = kbase + (r & 3) + 8 * (r >> 2) + 4 * hi;
                        pe0[r] = (kl > qrow) ? 0.f : exp2f(st0[r]);
                        pe1[r] = (kl + 32 > qrow) ? 0.f : exp2f(st1[r]);
                    }
                }
#pragma unroll
                for (int r = 0; r < 16; ++r) ls += pe0[r] + pe1[r];

                // in-register P -> A-fragments (T12)
                v8s pa0 = build_pa(pe0[0], pe0[1], pe0[2], pe0[3],
                                   pe0[4], pe0[5], pe0[6], pe0[7]);
                v8s pa1 = build_pa(pe0[8], pe0[9], pe0[10], pe0[11],
                                   pe0[12], pe0[13], pe0[14], pe0[15]);
                v8s pa2 = build_pa(pe1[0], pe1[1], pe1[2], pe1[3],
                                   pe1[4], pe1[5], pe1[6], pe1[7]);
                v8s pa3 = build_pa(pe1[8], pe1[9], pe1[10], pe1[11],
                                   pe1[12], pe1[13], pe1[14], pe1[15]);

                // PV: O[q][d], two d-tiles (o0: d 0..31, o1: d 32..63)
#pragma unroll
                for (int kc = 0; kc < 4; ++kc) {
                    v8s pav = (kc == 0) ? pa0 : (kc == 1) ? pa1
                              : (kc == 2) ? pa2 : pa3;
                    const int ks = k2 * 8 + kc * 2 + hi;  // 16B key-slot
                    const int d0 = l31, d1 = 32 + l31;
                    v8s vf0 = *(const v8s*)
                        &Vs[d0 * 128 + ((ks ^ VXOR(d0)) << 3)];
                    v8s vf1 = *(const v8s*)
                        &Vs[d1 * 128 + ((ks ^ VXOR(d1)) << 3)];
                    o0 = __builtin_amdgcn_mfma_f32_32x32x16_bf16(
                        pav, vf0, o0, 0, 0, 0);
                    o1 = __builtin_amdgcn_mfma_f32_32x32x16_bf16(
                        pav, vf1, o1, 0, 0, 0);
                }
            }
        }

        // close row-sums (lane + partner half), normalize, store
        ls += __shfl_xor(ls, 32, 64);
        float inv = 1.f / ls;
#pragma unroll
        for (int r = 0; r < 16; ++r) {
            int m = (r & 3) + 8 * (r >> 2) + 4 * hi;
            float im = __shfl(inv, m, 64);
            size_t idx = ((size_t)(b * SEQ + q0w + m)) * DMODEL
                         + h * HDIM + l31;
            Cx[idx] = f2bf(o0[r] * im);
            Cx[idx + 32] = f2bf(o1[r] * im);
        }
    }
}

// ---------------------------------------------------------------------------
// Stage 3: out = Cx @ W_o + b_o. Both operands async, BK=64.
// ---------------------------------------------------------------------------
__global__ __launch_bounds__(256, 2)
void out_gemm(const u16* __restrict__ Cx, const u16* __restrict__ WoT,
              const float* __restrict__ bo, float* __restrict__ Y)
{
    __shared__ __align__(16) short As[128 * 64];
    __shared__ __align__(16) short Bs[128 * 64];

    const int n0 = blockIdx.x * 128;
    const int m0 = blockIdx.y * 128;
    const int t = threadIdx.x;
    const int lane = t & 63;
    const int l15 = lane & 15;
    const int quad = lane >> 4;
    const int wave = t >> 6;
    const int wm = (wave >> 1) * 64;
    const int wn = (wave & 1) * 64;
    const int srow = t >> 3;
    const int sc8 = (t & 7) * 8;

    v4f acc[4][4];
#pragma unroll
    for (int i = 0; i < 4; ++i)
#pragma unroll
        for (int j = 0; j < 4; ++j) acc[i][j] = {0.f, 0.f, 0.f, 0.f};

    for (int k0 = 0; k0 < DMODEL; k0 += 64) {
        __syncthreads();
#pragma unroll
        for (int c = 0; c < 4; ++c) {
            g2l16(&Cx[(size_t)(m0 + c * 32 + srow) * DMODEL + k0 + sc8],
                  &As[(c * 32 + srow) * 64 + sc8]);
            g2l16(&WoT[(size_t)(n0 + c * 32 + srow) * DMODEL + k0 + sc8],
                  &Bs[(c * 32 + srow) * 64 + sc8]);
        }
        __syncthreads();

#pragma unroll
        for (int kh = 0; kh < 2; ++kh) {
            v8s af[4], bf[4];
#pragma unroll
            for (int i = 0; i < 4; ++i)
                af[i] = *(const v8s*)
                    &As[(wm + i * 16 + l15) * 64 + kh * 32 + quad * 8];
#pragma unroll
            for (int j = 0; j < 4; ++j)
                bf[j] = *(const v8s*)
                    &Bs[(wn + j * 16 + l15) * 64 + kh * 32 + quad * 8];
#pragma unroll
            for (int i = 0; i < 4; ++i)
#pragma unroll
                for (int j = 0; j < 4; ++j)
                    acc[i][j] = __builtin_amdgcn_mfma_f32_16x16x32_bf16(
                        af[i], bf[j], acc[i][j], 0, 0, 0);
        }
    }

#pragma unroll
    for (int i = 0; i < 4; ++i)
#pragma unroll
        for (int j = 0; j < 4; ++j) {
            int col = n0 + wn + j * 16 + l15;
            float bias = bo[col];
#pragma unroll
            for (int r = 0; r < 4; ++r) {
                int m = m0 + wm + i * 16 + quad * 4 + r;
                Y[(size_t)m * DMODEL + col] = acc[i][j][r] + bias;
            }
        }
}

// ---------------------------------------------------------------------------
extern "C" void kernel_launch(void* const* d_in, const int* in_sizes, int n_in,
                              void* d_out, int out_size, void* d_ws,
                              size_t ws_size, hipStream_t stream)
{
    const float* x  = (const float*)d_in[0];
    const float* Wq = (const float*)d_in[1];
    const float* Wk = (const float*)d_in[2];
    const float* Wv = (const float*)d_in[3];
    const float* Wo = (const float*)d_in[4];
    const float* bo = (const float*)d_in[5];
    float* Y = (float*)d_out;

    const size_t per = (size_t)BATCH * NHEADS * SEQ * HDIM;  // 8M elems
    const size_t wsz = (size_t)DMODEL * DMODEL;              // 1M elems
    u16* base = (u16*)d_ws;

    if (ws_size >= (size_t)72 * 1024 * 1024) {
        u16* xb  = base;
        u16* Cx  = base;                 // aliases xb (dead after qkv)
        u16* Wt4 = base + per;           // 4 transposed weights
        u16* Qb  = base + per + 4 * wsz;
        u16* Kb  = Qb + per;
        u16* Vt  = Kb + per;

        prep<<<1024 + MTOT * DMODEL / (256 * 8), 256, 0, stream>>>(
            x, xb, Wq, Wk, Wv, Wo, Wt4);
        qkv_fast<<<dim3(24, MTOT / 256), 512, 0, stream>>>(
            xb, Wt4, Qb, Kb, Vt);
        attn<<<512, 256, 0, stream>>>(Qb, Kb, Vt, Cx);
        out_gemm<<<dim3(DMODEL / 128, MTOT / 128), 256, 0, stream>>>(
            Cx, Wt4 + 3 * wsz, bo, Y);
    } else {
        u16* Wt  = base;              // 3 weights [0,6MB)
        u16* Cx  = base;              // aliases Wt (dead after qkv)
        u16* Qb  = base + per;
        u16* WoT = base + per;        // aliases Qb after attn
        u16* Kb  = base + 2 * per;
        u16* Vt  = base + 3 * per;

        transpose_w<<<dim3(16, 16), 256, 0, stream>>>(Wq, Wt);
        transpose_w<<<dim3(16, 16), 256, 0, stream>>>(Wk, Wt + wsz);
        transpose_w<<<dim3(16, 16), 256, 0, stream>>>(Wv, Wt + 2 * wsz);
        qkv_slow<<<dim3(DMODEL / 128, MTOT / 128, 3), 256, 0, stream>>>(
            x, Wt, Qb, Kb, Vt);
        attn<<<512, 256, 0, stream>>>(Qb, Kb, Vt, Cx);
        transpose_w<<<dim3(16, 16), 256, 0, stream>>>(Wo, WoT);
        out_gemm<<<dim3(DMODEL / 128, MTOT / 128), 256, 0, stream>>>(
            Cx, WoT, bo, Y);
    }
}